// Round 17
// baseline (405.397 us; speedup 1.0000x reference)
//
#include <hip/hip_runtime.h>
#include <hip/hip_bf16.h>
#include <math.h>
#include <stdint.h>

typedef __bf16 bf16;
typedef __attribute__((ext_vector_type(8))) __bf16 bf16x8;
typedef __attribute__((ext_vector_type(4))) float f32x4;

typedef __attribute__((address_space(1))) void gas_void;
typedef __attribute__((address_space(3))) void las_void;

#define DEV __device__ __forceinline__

static constexpr int B_ = 8, N_ = 577, D_ = 768, H_ = 12;
static constexpr int M_ = B_ * N_;   // 4616 rows
static constexpr int MP_ = 4736;     // padded to 37*128 for GEMM tiles
static constexpr int NP_ = 640;      // padded N for attention tiles
static constexpr int BH_ = B_ * H_;  // 96
static constexpr float SCALE_ = 0.125f;  // 64^-0.5

DEV void async_cp16(const void* g, void* l) {
  __builtin_amdgcn_global_load_lds((gas_void*)g, (las_void*)l, 16, 0, 0);
}
DEV float fast_rcp(float x) { return __builtin_amdgcn_rcpf(x); }
DEV float elu1(float x) { return x > 0.0f ? x + 1.0f : __expf(x); }
// tanh-form GELU: x * sigmoid(1.5957691*x*(1 + 0.044715*x^2)); max dev ~1e-3
DEV float fast_gelu(float x) {
  const float x2 = x * x;
  const float z = x * fmaf(0.0713548826f, x2, 1.5957691216f);
  return x * fast_rcp(1.0f + __expf(-z));
}

// ---------------- fused f32 -> bf16 convert, 6 segments ----------------
__global__ __launch_bounds__(256) void cvt6_kernel(
    const float* __restrict__ s0, const float* __restrict__ s1,
    const float* __restrict__ s2, const float* __restrict__ s3,
    const float* __restrict__ s4, const float* __restrict__ s5,
    bf16* __restrict__ d0, bf16* __restrict__ d1, bf16* __restrict__ d2,
    bf16* __restrict__ d3, bf16* __restrict__ d4, bf16* __restrict__ d5,
    int n0, int n1, int n2, int n3, int n4c, int n5) {
  const float* ss[6] = {s0, s1, s2, s3, s4, s5};
  bf16* dd[6] = {d0, d1, d2, d3, d4, d5};
  const int nn[6] = {n0, n1, n2, n3, n4c, n5};
  int bid = blockIdx.x;
  int seg = 0;
#pragma unroll 6
  for (int k = 0; k < 6; k++) {
    const int nb = (nn[k] + 255) >> 8;
    if (bid < nb) { seg = k; break; }
    bid -= nb;
  }
  const int i = bid * 256 + threadIdx.x;
  if (i < nn[seg]) {
    const float4 v = ((const float4*)ss[seg])[i];
    bf16 o[4] = {(bf16)v.x, (bf16)v.y, (bf16)v.z, (bf16)v.w};
    *(uint64_t*)(dd[seg] + (size_t)i * 4) = *(const uint64_t*)o;
  }
}

// ---------------- dual LayerNorm (both streams, one dispatch) ----------------
__global__ __launch_bounds__(256) void ln2_kernel(
    const float* __restrict__ x0, const float* __restrict__ x1,
    const float* __restrict__ w, const float* __restrict__ bp,
    bf16* __restrict__ out) {  // out: [2*MP][768] stacked
  const int row = blockIdx.x;            // 0..2M-1
  const int st = (int)(row >= M_);
  const int srow = row - st * M_;
  const float* xr = (st ? x1 : x0) + (size_t)srow * D_;
  const int t = threadIdx.x;
  float v0 = xr[t], v1 = xr[t + 256], v2 = xr[t + 512];
  float s = v0 + v1 + v2;
  float ss = v0 * v0 + v1 * v1 + v2 * v2;
#pragma unroll
  for (int m = 32; m >= 1; m >>= 1) {
    s += __shfl_down(s, m);
    ss += __shfl_down(ss, m);
  }
  __shared__ float red[8];
  if ((t & 63) == 0) { red[t >> 6] = s; red[4 + (t >> 6)] = ss; }
  __syncthreads();
  s = red[0] + red[1] + red[2] + red[3];
  ss = red[4] + red[5] + red[6] + red[7];
  const float mu = s * (1.0f / D_);
  float var = ss * (1.0f / D_) - mu * mu;
  var = fmaxf(var, 0.0f);
  const float rs = rsqrtf(var + 1e-5f);
  bf16* orow = out + ((size_t)st * MP_ + srow) * D_;
  orow[t]       = (bf16)((v0 - mu) * rs * w[t]       + bp[t]);
  orow[t + 256] = (bf16)((v1 - mu) * rs * w[t + 256] + bp[t + 256]);
  orow[t + 512] = (bf16)((v2 - mu) * rs * w[t + 512] + bp[t + 512]);
}

// ---------------- dual-stream GEMM: 128^2 tile, BK=64, 2-phase dbuf ----------------
// Measured optimum (R13/R14): halved barrier events vs BK=32, XOR-(row&7)
// swizzle (bank-conflict-free), band-of-4 L2 supertile, XCD remap, 2 blk/CU.
enum { EP_BF16 = 0, EP_PROJ = 1, EP_GELU = 2, EP_FC2 = 3 };

template <int EP, int K>
__global__ __launch_bounds__(256) void gemm_bt(
    const bf16* __restrict__ A, const bf16* __restrict__ W0,
    const bf16* __restrict__ W1, int Nn, int gx,
    const float* __restrict__ bias0, const float* __restrict__ bias1,
    const float* __restrict__ gamma,
    const float* __restrict__ resid0, const float* __restrict__ resid1,
    bf16* __restrict__ Cb, float* __restrict__ Cf0, float* __restrict__ Cf1) {
  __shared__ __align__(16) bf16 As[2][128 * 64];
  __shared__ __align__(16) bf16 Bs[2][128 * 64];
  // bijective XCD remap (m204): XCD k owns a contiguous flat range
  const int nwg = gridDim.x;
  const int o = blockIdx.x;
  const int q = nwg >> 3, r = nwg & 7, xcd = o & 7;
  const int flat = (xcd < r ? xcd * (q + 1) : r * (q + 1) + (xcd - r) * q) + (o >> 3);
  // band-of-4 decode: consecutive flats cycle 4 A row-tiles under one W tile
  const int gyv = nwg / gx;
  const int fb = gyv >> 2;        // full 4-row bands
  const int bsz = gx << 2;
  int bx, by;
  if (flat < fb * bsz) {
    const int band = flat / bsz, rr2 = flat - band * bsz;
    bx = rr2 >> 2;
    by = band * 4 + (rr2 & 3);
  } else {
    const int rows = gyv - (fb << 2);
    const int rr2 = flat - fb * bsz;
    bx = rr2 / rows;
    by = (fb << 2) + (rr2 - bx * rows);
  }

  const int t = threadIdx.x;
  const int lane = t & 63, wv = t >> 6;
  const int ln = lane & 15, kg = lane >> 4;
  const int wr = wv >> 1, wc = wv & 1;
  const int s = (int)(by >= (MP_ / 128));
  const bf16* W = s ? W1 : W0;
  const size_t brow = (size_t)by * 128;
  const size_t bcol = (size_t)bx * 128;

  // staging: thread t owns (row rA + q*32, 16B-slot sl); source column
  // pre-swizzled so LDS[row][sl] = global[row][sl ^ (row&7)].
  const int rA = t >> 3, sl = t & 7;
  const int swsl = (sl ^ (rA & 7)) * 8;
  const bf16* Asrc = A + (brow + rA) * (size_t)K + swsl;
  const bf16* Wsrc = W + (bcol + rA) * (size_t)K + swsl;

  auto stage = [&](int buf, int kk) {
#pragma unroll
    for (int q2 = 0; q2 < 4; q2++) {
      async_cp16(Asrc + (size_t)q2 * 32 * K + kk, &As[buf][(q2 * 256 + wv * 64) * 8]);
      async_cp16(Wsrc + (size_t)q2 * 32 * K + kk, &Bs[buf][(q2 * 256 + wv * 64) * 8]);
    }
  };

  f32x4 acc[4][4] = {};
  constexpr int nt = K >> 6;
  static_assert(K % 64 == 0, "K must be a multiple of 64");
  stage(0, 0);
  __syncthreads();
#pragma unroll 1
  for (int tt = 0; tt < nt; ++tt) {
    if (tt + 1 < nt) stage((tt + 1) & 1, (tt + 1) * 64);
    const int bb = tt & 1;
#pragma unroll
    for (int kh = 0; kh < 2; kh++) {
      bf16x8 af[4], bfr[4];
#pragma unroll
      for (int i = 0; i < 4; i++) {
        const int row = wr * 64 + i * 16 + ln;
        af[i] = *(const bf16x8*)&As[bb][row * 64 + (((kh * 4 + kg) ^ (ln & 7)) * 8)];
      }
#pragma unroll
      for (int j = 0; j < 4; j++) {
        const int row = wc * 64 + j * 16 + ln;
        bfr[j] = *(const bf16x8*)&Bs[bb][row * 64 + (((kh * 4 + kg) ^ (ln & 7)) * 8)];
      }
#pragma unroll
      for (int i = 0; i < 4; i++)
#pragma unroll
        for (int j = 0; j < 4; j++)
          acc[i][j] = __builtin_amdgcn_mfma_f32_16x16x32_bf16(af[i], bfr[j], acc[i][j], 0, 0, 0);
    }
    __syncthreads();  // drains this step's stage (own-wave vmcnt(0)) + read fence
  }

  const float* biasS = s ? bias1 : bias0;
  const float* residS = s ? resid1 : resid0;
  float* CfS = s ? Cf1 : Cf0;
  // D layout: row = (lane>>4)*4 + r, col = lane&15
#pragma unroll
  for (int i = 0; i < 4; i++) {
    const int rb = (int)brow + wr * 64 + i * 16 + kg * 4;
#pragma unroll
    for (int j = 0; j < 4; j++) {
      const int col = (int)bcol + wc * 64 + j * 16 + ln;
#pragma unroll
      for (int rr = 0; rr < 4; rr++) {
        const int row = rb + rr;  // combined-row index
        float v = acc[i][j][rr];
        if (EP == EP_BF16) {
          Cb[(size_t)row * Nn + col] = (bf16)v;
        } else if (EP == EP_GELU) {
          v += biasS[col];
          Cb[(size_t)row * Nn + col] = (bf16)fast_gelu(v);
        } else {
          const int r2 = row - s * MP_;
          if (r2 < M_) {
            v += biasS[col];
            if (EP == EP_PROJ) {
              CfS[(size_t)r2 * Nn + col] = residS[(size_t)r2 * Nn + col] + gamma[col] * v;
            } else {  // EP_FC2
              CfS[(size_t)r2 * Nn + col] += gamma[col] * v;
            }
          }
        }
      }
    }
  }
}

// ---------------- prep: qkv (raw bf16) -> attention operands ----------------
__global__ __launch_bounds__(256) void prep_kernel(
    const bf16* __restrict__ qm, const bf16* __restrict__ qc,
    bf16* __restrict__ Qcat, bf16* __restrict__ Kcat,
    bf16* __restrict__ Vt, bf16* __restrict__ CVt,
    float* __restrict__ rowt, float* __restrict__ colt) {
  const int n0 = blockIdx.x * 64;
  const int h = blockIdx.y, b = blockIdx.z;
  const int bh = b * H_ + h;
  const int t = threadIdx.x;
  const int nl = t >> 2, c = t & 3;
  const int n = n0 + nl;
  const bool valid = n < N_;
  __shared__ bf16 vts[64][72], cvts[64][72];
  float q2 = 0.f, cqs = 0.f, k2 = 0.f, cks = 0.f;
  bf16 qo[16], sqo[16], ko[16], sko[16];
  if (valid) {
    const size_t ro = (size_t)(b * N_ + n) * 2304 + h * 64 + c * 16;
#pragma unroll
    for (int half = 0; half < 2; half++) {
      bf16x8 qv8 = *(const bf16x8*)(qm + ro + half * 8);
      bf16x8 kv8 = *(const bf16x8*)(qm + ro + 768 + half * 8);
      bf16x8 vv8 = *(const bf16x8*)(qm + ro + 1536 + half * 8);
      bf16x8 cq8 = *(const bf16x8*)(qc + ro + half * 8);
      bf16x8 ck8 = *(const bf16x8*)(qc + ro + 768 + half * 8);
      bf16x8 cv8 = *(const bf16x8*)(qc + ro + 1536 + half * 8);
#pragma unroll
      for (int i = 0; i < 8; i++) {
        const int d = half * 8 + i;
        float qv = (float)qv8[i] * SCALE_;
        float kv = (float)kv8[i];
        float cq1 = elu1((float)cq8[i]);
        float ck1 = elu1((float)ck8[i]);
        q2 += qv * qv; cqs += cq1; k2 += kv * kv; cks += ck1;
        qo[d] = (bf16)qv; sqo[d] = (bf16)sqrtf(fmaxf(cq1, 1e-24f));
        ko[d] = (bf16)kv; sko[d] = (bf16)sqrtf(fmaxf(ck1, 1e-24f));
        vts[nl][c * 16 + d] = vv8[i];
        cvts[nl][c * 16 + d] = (bf16)elu1((float)cv8[i]);
      }
    }
  } else {
#pragma unroll
    for (int d = 0; d < 16; d++) {
      qo[d] = (bf16)0.f; sqo[d] = (bf16)0.f; ko[d] = (bf16)0.f; sko[d] = (bf16)0.f;
      vts[nl][c * 16 + d] = (bf16)0.f; cvts[nl][c * 16 + d] = (bf16)0.f;
    }
  }
  {
    bf16* qrow = Qcat + ((size_t)bh * NP_ + n) * 128;
    bf16* krow = Kcat + ((size_t)bh * NP_ + n) * 128;
#pragma unroll
    for (int d = 0; d < 16; d++) {
      qrow[c * 16 + d] = qo[d];
      qrow[64 + c * 16 + d] = sqo[d];
      krow[c * 16 + d] = ko[d];
      krow[64 + c * 16 + d] = sko[d];
    }
  }
  float rt = q2 + cqs, ct = k2 + cks;
  rt += __shfl_xor(rt, 1); rt += __shfl_xor(rt, 2);
  ct += __shfl_xor(ct, 1); ct += __shfl_xor(ct, 2);
  if (c == 0) { rowt[(size_t)bh * NP_ + n] = rt; colt[(size_t)bh * NP_ + n] = ct; }
  __syncthreads();
  const int drow = t >> 2;
  const size_t vb = ((size_t)bh * 64 + drow) * NP_ + n0 + c * 16;
#pragma unroll
  for (int i = 0; i < 16; i++) {
    Vt[vb + i] = vts[c * 16 + i][drow];
    CVt[vb + i] = cvts[c * 16 + i][drow];
  }
}

// ---------------- fused attention: 128 Q-rows per block (2 i-halves) ----------------
// GEMM-proven amortization applied to attention: per j-tile, stage K/V/CV once
// and compute BOTH 64-row Q-halves against it -> fixed staging/barrier cost per
// unit compute halves; K/V/CV traffic halves (5 passes instead of 10 per bh).
// Grid 480 = 96 bh x 5 i-blocks, XCD-grouped (60/XCD). Ps reused across halves
// (wave-private rows, no barrier needed between halves).
__global__ __launch_bounds__(256) void attn_kernel(
    const bf16* __restrict__ Qcat, const bf16* __restrict__ Kcat,
    const bf16* __restrict__ Vt, const bf16* __restrict__ CVt,
    const float* __restrict__ rowt, const float* __restrict__ colt,
    const bf16* __restrict__ bias,
    bf16* __restrict__ ctxm, bf16* __restrict__ ctxc) {
  const int id = blockIdx.x;            // 0..479
  const int xcd = id & 7, slot = id >> 3;
  const int g = xcd + 8 * (slot / 5);   // bh 0..95
  const int it = slot % 5;
  const int b = g / H_, h = g % H_;
  const int bh = g;
  const int i0 = it * 128;
  const int t = threadIdx.x;
  const int lane = t & 63, w = t >> 6;
  const int ln = lane & 15, kg = lane >> 4;
  __shared__ __align__(16) bf16 Ks[2][64 * 128];  // prologue: hosts the 2 Q halves
  __shared__ __align__(16) bf16 Vs[2][64 * 64];
  __shared__ __align__(16) bf16 CVs[2][64 * 64];
  __shared__ __align__(16) bf16 Ps[64 * 72];

  const bf16* Qg = Qcat + (size_t)bh * NP_ * 128;
  const bf16* Kg = Kcat + (size_t)bh * NP_ * 128;
  const bf16* Vg = Vt + (size_t)bh * 64 * NP_;
  const bf16* CVg = CVt + (size_t)bh * 64 * NP_;

  auto stageK = [&](int buf, int j0) {
#pragma unroll
    for (int qq = 0; qq < 4; qq++) {
      const int idx = qq * 256 + t;
      const int row = idx >> 4, sl = idx & 15;
      async_cp16(Kg + (size_t)(j0 + row) * 128 + ((sl ^ (row & 7)) * 8),
                 &Ks[buf][(qq * 256 + w * 64) * 8]);
    }
  };
  auto stageV = [&](int buf, int j0) {
#pragma unroll
    for (int qq = 0; qq < 2; qq++) {
      const int idx = qq * 256 + t;
      const int row = idx >> 3, sl = idx & 7;
      async_cp16(Vg + (size_t)row * NP_ + j0 + ((sl ^ (row & 7)) * 8),
                 &Vs[buf][(qq * 256 + w * 64) * 8]);
      async_cp16(CVg + (size_t)row * NP_ + j0 + ((sl ^ (row & 7)) * 8),
                 &CVs[buf][(qq * 256 + w * 64) * 8]);
    }
  };

  // prologue: Q half0 -> Ks[0], Q half1 -> Ks[1]
#pragma unroll
  for (int hf = 0; hf < 2; hf++) {
#pragma unroll
    for (int qq = 0; qq < 4; qq++) {
      const int idx = qq * 256 + t;
      const int row = idx >> 4, sl = idx & 15;
      async_cp16(Qg + (size_t)(i0 + hf * 64 + row) * 128 + ((sl ^ (row & 7)) * 8),
                 &Ks[hf][(qq * 256 + w * 64) * 8]);
    }
  }
  __syncthreads();
  bf16x8 aq[2][4];
#pragma unroll
  for (int hf = 0; hf < 2; hf++) {
    const int row = w * 16 + ln;
#pragma unroll
    for (int kc = 0; kc < 4; kc++) {
      const int slot2 = kc * 4 + kg;
      aq[hf][kc] = *(const bf16x8*)&Ks[hf][row * 128 + ((slot2 ^ (row & 7)) * 8)];
    }
  }
  float rt2[2][4];
#pragma unroll
  for (int hf = 0; hf < 2; hf++)
#pragma unroll
    for (int r = 0; r < 4; r++)
      rt2[hf][r] = rowt[(size_t)bh * NP_ + i0 + hf * 64 + w * 16 + kg * 4 + r];
  __syncthreads();  // all waves done reading Q before K(0) overwrites the buffers
  stageK(1, 0);     // K(jt) lives in Ks[(jt+1)&1]
  stageV(0, 0);     // V/CV(jt) in buf jt&1
  __syncthreads();  // K(0)/V(0) landed

  f32x4 accm[2][4] = {}, accc[2][4] = {};
  float den[2][4] = {};

  for (int jt = 0; jt < 10; jt++) {
    const int j0 = jt * 64;
    const int kc2 = (jt + 1) & 1;
    const int vc2 = jt & 1;
    if (jt + 1 < 10) {
      stageK(jt & 1, j0 + 64);
      stageV((jt + 1) & 1, j0 + 64);
    }
    float ctb[4];
#pragma unroll
    for (int js = 0; js < 4; js++)
      ctb[js] = colt[(size_t)bh * NP_ + j0 + js * 16 + ln];
#pragma unroll
    for (int hf = 0; hf < 2; hf++) {
      const int igb = i0 + hf * 64 + w * 16 + kg * 4;
      // bias prefetch for this half
      float bb[4][4];
#pragma unroll
      for (int js = 0; js < 4; js++) {
        const int jg = j0 + js * 16 + ln;
        const int jc = jg < N_ ? jg : N_ - 1;
#pragma unroll
        for (int r = 0; r < 4; r++) {
          const int ic = (igb + r) < N_ ? (igb + r) : N_ - 1;
          bb[js][r] = (float)bias[((size_t)h * N_ + ic) * N_ + jc];
        }
      }
      // QK^T for this half
#pragma unroll
      for (int js = 0; js < 4; js++) {
        f32x4 sv = {};
#pragma unroll
        for (int kc = 0; kc < 4; kc++) {
          const int row = js * 16 + ln;
          const int slot2 = kc * 4 + kg;
          bf16x8 bk = *(const bf16x8*)&Ks[kc2][row * 128 + ((slot2 ^ (row & 7)) * 8)];
          sv = __builtin_amdgcn_mfma_f32_16x16x32_bf16(aq[hf][kc], bk, sv, 0, 0, 0);
        }
        const int jg = j0 + js * 16 + ln;
#pragma unroll
        for (int r = 0; r < 4; r++) {
          const float S = 2.0f * sv[r] - rt2[hf][r] - ctb[js];
          const float sig = fast_rcp(1.0f + __expf(-S));
          float e = __expf(sig + bb[js][r]);
          if (jg >= N_) e = 0.0f;
          const bf16 eb = (bf16)e;
          den[hf][r] += (float)eb;
          Ps[(w * 16 + kg * 4 + r) * 72 + js * 16 + ln] = eb;
        }
      }
      // PV for this half (Ps rows wave-private: no barrier between halves)
#pragma unroll
      for (int ks = 0; ks < 2; ks++) {
        const int prow = w * 16 + ln;
        bf16x8 pa = *(const bf16x8*)&Ps[prow * 72 + ks * 32 + kg * 8];
        bf16x8 p2a;
#pragma unroll
        for (int i = 0; i < 8; i++) {
          const float pf = (float)pa[i];
          p2a[i] = (bf16)(pf * pf);
        }
#pragma unroll
        for (int nt = 0; nt < 4; nt++) {
          const int vrow = nt * 16 + ln;
          const int slot2 = ks * 4 + kg;
          bf16x8 vb = *(const bf16x8*)&Vs[vc2][vrow * 64 + ((slot2 ^ (vrow & 7)) * 8)];
          bf16x8 cvb = *(const bf16x8*)&CVs[vc2][vrow * 64 + ((slot2 ^ (vrow & 7)) * 8)];
          accm[hf][nt] = __builtin_amdgcn_mfma_f32_16x16x32_bf16(pa, vb, accm[hf][nt], 0, 0, 0);
          accc[hf][nt] = __builtin_amdgcn_mfma_f32_16x16x32_bf16(p2a, cvb, accc[hf][nt], 0, 0, 0);
        }
      }
    }
    __syncthreads();  // ONE barrier per tile: drains next-tile stages + read fence
  }
#pragma unroll
  for (int hf = 0; hf < 2; hf++)
#pragma unroll
    for (int r = 0; r < 4; r++) {
      float d = den[hf][r];
      d += __shfl_xor(d, 1); d += __shfl_xor(d, 2);
      d += __shfl_xor(d, 4); d += __shfl_xor(d, 8);
      den[hf][r] = d;
    }
#pragma unroll
  for (int hf = 0; hf < 2; hf++)
#pragma unroll
    for (int r = 0; r < 4; r++) {
      const int ig = i0 + hf * 64 + w * 16 + kg * 4 + r;
      if (ig < N_) {
        const float inv = fast_rcp(den[hf][r]);
        const float inv2 = inv * inv;
        const size_t base = (size_t)(b * N_ + ig) * D_ + h * 64;
#pragma unroll
        for (int nt = 0; nt < 4; nt++) {
          ctxm[base + nt * 16 + ln] = (bf16)(accm[hf][nt][r] * inv);
          ctxc[base + nt * 16 + ln] = (bf16)(accc[hf][nt][r] * inv2);
        }
      }
    }
}

// ---------------- host launch ----------------
extern "C" void kernel_launch(void* const* d_in, const int* in_sizes, int n_in,
                              void* d_out, int out_size, void* d_ws, size_t ws_size,
                              hipStream_t stream) {
  const float* x_mean = (const float*)d_in[0];
  const float* x_cov  = (const float*)d_in[1];
  const float* rpb    = (const float*)d_in[2];
  const float* n1w    = (const float*)d_in[3];
  const float* n1b    = (const float*)d_in[4];
  const float* qkvw   = (const float*)d_in[5];
  const float* projw  = (const float*)d_in[6];
  const float* projb  = (const float*)d_in[7];
  const float* cprojw = (const float*)d_in[8];
  const float* cprojb = (const float*)d_in[9];
  const float* n2w    = (const float*)d_in[10];
  const float* n2b    = (const float*)d_in[11];
  const float* fc1w   = (const float*)d_in[12];
  const float* fc1b   = (const float*)d_in[13];
  const float* fc2w   = (const float*)d_in[14];
  const float* fc2b   = (const float*)d_in[15];
  const float* g1     = (const float*)d_in[16];
  const float* g2     = (const float*)d_in[17];
  (void)in_sizes; (void)n_in; (void)out_size; (void)ws_size;

  char* ws = (char*)d_ws;
  size_t off = 0;
  auto take = [&](size_t bytes) {
    char* p = ws + off;
    off += (bytes + 255) & ~(size_t)255;
    return p;
  };
  bf16* wq   = (bf16*)take((size_t)2304 * 768 * 2);
  bf16* wp   = (bf16*)take((size_t)768 * 768 * 2);
  bf16* wcp  = (bf16*)take((size_t)768 * 768 * 2);
  bf16* wf1  = (bf16*)take((size_t)3072 * 768 * 2);
  bf16* wf2  = (bf16*)take((size_t)768 * 3072 * 2);
  bf16* xln  = (bf16*)take((size_t)2 * MP_ * 768 * 2);   // LN out, streams stacked
  char* R    = take((size_t)2 * MP_ * 3072 * 2);          // qkv / mlp-hidden union
  bf16* qkvb = (bf16*)R;                                  // [2MP][2304]
  bf16* hbuf = (bf16*)R;                                  // [2MP][3072]
  bf16* biasb = (bf16*)(R + (size_t)2 * MP_ * 2304 * 2);  // tail gap of R
  bf16* Qcat = (bf16*)take((size_t)BH_ * NP_ * 128 * 2);
  bf16* Kcat = (bf16*)take((size_t)BH_ * NP_ * 128 * 2);
  bf16* Vt   = (bf16*)take((size_t)BH_ * 64 * NP_ * 2);
  bf16* CVt  = (bf16*)take((size_t)BH_ * 64 * NP_ * 2);
  float* rowt = (float*)take((size_t)BH_ * NP_ * 4);
  float* colt = (float*)take((size_t)BH_ * NP_ * 4);
  bf16* ctx  = (bf16*)take((size_t)2 * MP_ * 768 * 2);    // attn out, streams stacked

  float* outm = (float*)d_out;
  float* outc = outm + (size_t)M_ * D_;

  // all weight/bias converts in ONE dispatch
  {
    const int c0 = 2304 * 768 / 4, c1 = 768 * 768 / 4, c2 = 768 * 768 / 4;
    const int c3 = 3072 * 768 / 4, c4 = 768 * 3072 / 4, c5 = H_ * N_ * N_ / 4;
    const int nb = ((c0 + 255) >> 8) + ((c1 + 255) >> 8) + ((c2 + 255) >> 8) +
                   ((c3 + 255) >> 8) + ((c4 + 255) >> 8) + ((c5 + 255) >> 8);
    cvt6_kernel<<<nb, 256, 0, stream>>>(qkvw, projw, cprojw, fc1w, fc2w, rpb,
                                        wq, wp, wcp, wf1, wf2, biasb,
                                        c0, c1, c2, c3, c4, c5);
  }
  // LN1 (both streams, one dispatch)
  ln2_kernel<<<2 * M_, 256, 0, stream>>>(x_mean, x_cov, n1w, n1b, xln);
  // qkv GEMM (both streams, one dispatch)
  gemm_bt<EP_BF16, 768><<<18 * 74, 256, 0, stream>>>(xln, wq, wq, 2304, 18,
      nullptr, nullptr, nullptr, nullptr, nullptr, qkvb, nullptr, nullptr);
  // attention operand prep
  prep_kernel<<<dim3(10, 12, 8), 256, 0, stream>>>(
      qkvb, qkvb + (size_t)MP_ * 2304, Qcat, Kcat, Vt, CVt, rowt, colt);
  // fused attention (XCD-grouped 1-D grid, 128 Q-rows/block)
  attn_kernel<<<480, 256, 0, stream>>>(Qcat, Kcat, Vt, CVt, rowt, colt, biasb,
                                       ctx, ctx + (size_t)MP_ * 768);
  // proj + residual (writes d_out), per-stream weights
  gemm_bt<EP_PROJ, 768><<<6 * 74, 256, 0, stream>>>(ctx, wp, wcp, 768, 6,
      projb, cprojb, g1, x_mean, x_cov, nullptr, outm, outc);
  // LN2 (both streams, reads d_out)
  ln2_kernel<<<2 * M_, 256, 0, stream>>>(outm, outc, n2w, n2b, xln);
  // fc1 + fast gelu (both streams)
  gemm_bt<EP_GELU, 768><<<24 * 74, 256, 0, stream>>>(xln, wf1, wf1, 3072, 24,
      fc1b, fc1b, nullptr, nullptr, nullptr, hbuf, nullptr, nullptr);
  // fc2, accumulate into d_out (both streams)
  gemm_bt<EP_FC2, 3072><<<6 * 74, 256, 0, stream>>>(hbuf, wf2, wf2, 768, 6,
      fc2b, fc2b, g2, nullptr, nullptr, nullptr, outm, outc);
}

// Round 18
// 348.384 us; speedup vs baseline: 1.1636x; 1.1636x over previous
//
#include <hip/hip_runtime.h>
#include <hip/hip_bf16.h>
#include <math.h>
#include <stdint.h>

typedef __bf16 bf16;
typedef __attribute__((ext_vector_type(8))) __bf16 bf16x8;
typedef __attribute__((ext_vector_type(4))) float f32x4;

typedef __attribute__((address_space(1))) void gas_void;
typedef __attribute__((address_space(3))) void las_void;

#define DEV __device__ __forceinline__

static constexpr int B_ = 8, N_ = 577, D_ = 768, H_ = 12;
static constexpr int M_ = B_ * N_;   // 4616 rows
static constexpr int MP_ = 4736;     // padded to 37*128 for GEMM tiles
static constexpr int NP_ = 640;      // padded N for attention tiles
static constexpr int BH_ = B_ * H_;  // 96
static constexpr float SCALE_ = 0.125f;  // 64^-0.5

DEV void async_cp16(const void* g, void* l) {
  __builtin_amdgcn_global_load_lds((gas_void*)g, (las_void*)l, 16, 0, 0);
}
DEV float fast_rcp(float x) { return __builtin_amdgcn_rcpf(x); }
DEV float elu1(float x) { return x > 0.0f ? x + 1.0f : __expf(x); }
// tanh-form GELU: x * sigmoid(1.5957691*x*(1 + 0.044715*x^2)); max dev ~1e-3
DEV float fast_gelu(float x) {
  const float x2 = x * x;
  const float z = x * fmaf(0.0713548826f, x2, 1.5957691216f);
  return x * fast_rcp(1.0f + __expf(-z));
}

// ---------------- fused f32 -> bf16 convert, 6 segments ----------------
__global__ __launch_bounds__(256) void cvt6_kernel(
    const float* __restrict__ s0, const float* __restrict__ s1,
    const float* __restrict__ s2, const float* __restrict__ s3,
    const float* __restrict__ s4, const float* __restrict__ s5,
    bf16* __restrict__ d0, bf16* __restrict__ d1, bf16* __restrict__ d2,
    bf16* __restrict__ d3, bf16* __restrict__ d4, bf16* __restrict__ d5,
    int n0, int n1, int n2, int n3, int n4c, int n5) {
  const float* ss[6] = {s0, s1, s2, s3, s4, s5};
  bf16* dd[6] = {d0, d1, d2, d3, d4, d5};
  const int nn[6] = {n0, n1, n2, n3, n4c, n5};
  int bid = blockIdx.x;
  int seg = 0;
#pragma unroll 6
  for (int k = 0; k < 6; k++) {
    const int nb = (nn[k] + 255) >> 8;
    if (bid < nb) { seg = k; break; }
    bid -= nb;
  }
  const int i = bid * 256 + threadIdx.x;
  if (i < nn[seg]) {
    const float4 v = ((const float4*)ss[seg])[i];
    bf16 o[4] = {(bf16)v.x, (bf16)v.y, (bf16)v.z, (bf16)v.w};
    *(uint64_t*)(dd[seg] + (size_t)i * 4) = *(const uint64_t*)o;
  }
}

// ---------------- dual LayerNorm (both streams, one dispatch) ----------------
__global__ __launch_bounds__(256) void ln2_kernel(
    const float* __restrict__ x0, const float* __restrict__ x1,
    const float* __restrict__ w, const float* __restrict__ bp,
    bf16* __restrict__ out) {  // out: [2*MP][768] stacked
  const int row = blockIdx.x;            // 0..2M-1
  const int st = (int)(row >= M_);
  const int srow = row - st * M_;
  const float* xr = (st ? x1 : x0) + (size_t)srow * D_;
  const int t = threadIdx.x;
  float v0 = xr[t], v1 = xr[t + 256], v2 = xr[t + 512];
  float s = v0 + v1 + v2;
  float ss = v0 * v0 + v1 * v1 + v2 * v2;
#pragma unroll
  for (int m = 32; m >= 1; m >>= 1) {
    s += __shfl_down(s, m);
    ss += __shfl_down(ss, m);
  }
  __shared__ float red[8];
  if ((t & 63) == 0) { red[t >> 6] = s; red[4 + (t >> 6)] = ss; }
  __syncthreads();
  s = red[0] + red[1] + red[2] + red[3];
  ss = red[4] + red[5] + red[6] + red[7];
  const float mu = s * (1.0f / D_);
  float var = ss * (1.0f / D_) - mu * mu;
  var = fmaxf(var, 0.0f);
  const float rs = rsqrtf(var + 1e-5f);
  bf16* orow = out + ((size_t)st * MP_ + srow) * D_;
  orow[t]       = (bf16)((v0 - mu) * rs * w[t]       + bp[t]);
  orow[t + 256] = (bf16)((v1 - mu) * rs * w[t + 256] + bp[t + 256]);
  orow[t + 512] = (bf16)((v2 - mu) * rs * w[t + 512] + bp[t + 512]);
}

// ---------------- dual-stream GEMM: 128^2 tile, BK=64, 2-phase dbuf ----------------
// Measured optimum (R13/R14): halved barrier events vs BK=32, XOR-(row&7)
// swizzle (bank-conflict-free), band-of-4 L2 supertile, XCD remap, 2 blk/CU.
enum { EP_BF16 = 0, EP_PROJ = 1, EP_GELU = 2, EP_FC2 = 3 };

template <int EP, int K>
__global__ __launch_bounds__(256) void gemm_bt(
    const bf16* __restrict__ A, const bf16* __restrict__ W0,
    const bf16* __restrict__ W1, int Nn, int gx,
    const float* __restrict__ bias0, const float* __restrict__ bias1,
    const float* __restrict__ gamma,
    const float* __restrict__ resid0, const float* __restrict__ resid1,
    bf16* __restrict__ Cb, float* __restrict__ Cf0, float* __restrict__ Cf1) {
  __shared__ __align__(16) bf16 As[2][128 * 64];
  __shared__ __align__(16) bf16 Bs[2][128 * 64];
  // bijective XCD remap (m204): XCD k owns a contiguous flat range
  const int nwg = gridDim.x;
  const int o = blockIdx.x;
  const int q = nwg >> 3, r = nwg & 7, xcd = o & 7;
  const int flat = (xcd < r ? xcd * (q + 1) : r * (q + 1) + (xcd - r) * q) + (o >> 3);
  // band-of-4 decode: consecutive flats cycle 4 A row-tiles under one W tile
  const int gyv = nwg / gx;
  const int fb = gyv >> 2;        // full 4-row bands
  const int bsz = gx << 2;
  int bx, by;
  if (flat < fb * bsz) {
    const int band = flat / bsz, rr2 = flat - band * bsz;
    bx = rr2 >> 2;
    by = band * 4 + (rr2 & 3);
  } else {
    const int rows = gyv - (fb << 2);
    const int rr2 = flat - fb * bsz;
    bx = rr2 / rows;
    by = (fb << 2) + (rr2 - bx * rows);
  }

  const int t = threadIdx.x;
  const int lane = t & 63, wv = t >> 6;
  const int ln = lane & 15, kg = lane >> 4;
  const int wr = wv >> 1, wc = wv & 1;
  const int s = (int)(by >= (MP_ / 128));
  const bf16* W = s ? W1 : W0;
  const size_t brow = (size_t)by * 128;
  const size_t bcol = (size_t)bx * 128;

  // staging: thread t owns (row rA + q*32, 16B-slot sl); source column
  // pre-swizzled so LDS[row][sl] = global[row][sl ^ (row&7)].
  const int rA = t >> 3, sl = t & 7;
  const int swsl = (sl ^ (rA & 7)) * 8;
  const bf16* Asrc = A + (brow + rA) * (size_t)K + swsl;
  const bf16* Wsrc = W + (bcol + rA) * (size_t)K + swsl;

  auto stage = [&](int buf, int kk) {
#pragma unroll
    for (int q2 = 0; q2 < 4; q2++) {
      async_cp16(Asrc + (size_t)q2 * 32 * K + kk, &As[buf][(q2 * 256 + wv * 64) * 8]);
      async_cp16(Wsrc + (size_t)q2 * 32 * K + kk, &Bs[buf][(q2 * 256 + wv * 64) * 8]);
    }
  };

  f32x4 acc[4][4] = {};
  constexpr int nt = K >> 6;
  static_assert(K % 64 == 0, "K must be a multiple of 64");
  stage(0, 0);
  __syncthreads();
#pragma unroll 1
  for (int tt = 0; tt < nt; ++tt) {
    if (tt + 1 < nt) stage((tt + 1) & 1, (tt + 1) * 64);
    const int bb = tt & 1;
#pragma unroll
    for (int kh = 0; kh < 2; kh++) {
      bf16x8 af[4], bfr[4];
#pragma unroll
      for (int i = 0; i < 4; i++) {
        const int row = wr * 64 + i * 16 + ln;
        af[i] = *(const bf16x8*)&As[bb][row * 64 + (((kh * 4 + kg) ^ (ln & 7)) * 8)];
      }
#pragma unroll
      for (int j = 0; j < 4; j++) {
        const int row = wc * 64 + j * 16 + ln;
        bfr[j] = *(const bf16x8*)&Bs[bb][row * 64 + (((kh * 4 + kg) ^ (ln & 7)) * 8)];
      }
#pragma unroll
      for (int i = 0; i < 4; i++)
#pragma unroll
        for (int j = 0; j < 4; j++)
          acc[i][j] = __builtin_amdgcn_mfma_f32_16x16x32_bf16(af[i], bfr[j], acc[i][j], 0, 0, 0);
    }
    __syncthreads();  // drains this step's stage (own-wave vmcnt(0)) + read fence
  }

  const float* biasS = s ? bias1 : bias0;
  const float* residS = s ? resid1 : resid0;
  float* CfS = s ? Cf1 : Cf0;
  // D layout: row = (lane>>4)*4 + r, col = lane&15
#pragma unroll
  for (int i = 0; i < 4; i++) {
    const int rb = (int)brow + wr * 64 + i * 16 + kg * 4;
#pragma unroll
    for (int j = 0; j < 4; j++) {
      const int col = (int)bcol + wc * 64 + j * 16 + ln;
#pragma unroll
      for (int rr = 0; rr < 4; rr++) {
        const int row = rb + rr;  // combined-row index
        float v = acc[i][j][rr];
        if (EP == EP_BF16) {
          Cb[(size_t)row * Nn + col] = (bf16)v;
        } else if (EP == EP_GELU) {
          v += biasS[col];
          Cb[(size_t)row * Nn + col] = (bf16)fast_gelu(v);
        } else {
          const int r2 = row - s * MP_;
          if (r2 < M_) {
            v += biasS[col];
            if (EP == EP_PROJ) {
              CfS[(size_t)r2 * Nn + col] = residS[(size_t)r2 * Nn + col] + gamma[col] * v;
            } else {  // EP_FC2
              CfS[(size_t)r2 * Nn + col] += gamma[col] * v;
            }
          }
        }
      }
    }
  }
}

// ---------------- prep: qkv (raw bf16) -> attention operands ----------------
__global__ __launch_bounds__(256) void prep_kernel(
    const bf16* __restrict__ qm, const bf16* __restrict__ qc,
    bf16* __restrict__ Qcat, bf16* __restrict__ Kcat,
    bf16* __restrict__ Vt, bf16* __restrict__ CVt,
    float* __restrict__ rowt, float* __restrict__ colt) {
  const int n0 = blockIdx.x * 64;
  const int h = blockIdx.y, b = blockIdx.z;
  const int bh = b * H_ + h;
  const int t = threadIdx.x;
  const int nl = t >> 2, c = t & 3;
  const int n = n0 + nl;
  const bool valid = n < N_;
  __shared__ bf16 vts[64][72], cvts[64][72];
  float q2 = 0.f, cqs = 0.f, k2 = 0.f, cks = 0.f;
  bf16 qo[16], sqo[16], ko[16], sko[16];
  if (valid) {
    const size_t ro = (size_t)(b * N_ + n) * 2304 + h * 64 + c * 16;
#pragma unroll
    for (int half = 0; half < 2; half++) {
      bf16x8 qv8 = *(const bf16x8*)(qm + ro + half * 8);
      bf16x8 kv8 = *(const bf16x8*)(qm + ro + 768 + half * 8);
      bf16x8 vv8 = *(const bf16x8*)(qm + ro + 1536 + half * 8);
      bf16x8 cq8 = *(const bf16x8*)(qc + ro + half * 8);
      bf16x8 ck8 = *(const bf16x8*)(qc + ro + 768 + half * 8);
      bf16x8 cv8 = *(const bf16x8*)(qc + ro + 1536 + half * 8);
#pragma unroll
      for (int i = 0; i < 8; i++) {
        const int d = half * 8 + i;
        float qv = (float)qv8[i] * SCALE_;
        float kv = (float)kv8[i];
        float cq1 = elu1((float)cq8[i]);
        float ck1 = elu1((float)ck8[i]);
        q2 += qv * qv; cqs += cq1; k2 += kv * kv; cks += ck1;
        qo[d] = (bf16)qv; sqo[d] = (bf16)sqrtf(fmaxf(cq1, 1e-24f));
        ko[d] = (bf16)kv; sko[d] = (bf16)sqrtf(fmaxf(ck1, 1e-24f));
        vts[nl][c * 16 + d] = vv8[i];
        cvts[nl][c * 16 + d] = (bf16)elu1((float)cv8[i]);
      }
    }
  } else {
#pragma unroll
    for (int d = 0; d < 16; d++) {
      qo[d] = (bf16)0.f; sqo[d] = (bf16)0.f; ko[d] = (bf16)0.f; sko[d] = (bf16)0.f;
      vts[nl][c * 16 + d] = (bf16)0.f; cvts[nl][c * 16 + d] = (bf16)0.f;
    }
  }
  {
    bf16* qrow = Qcat + ((size_t)bh * NP_ + n) * 128;
    bf16* krow = Kcat + ((size_t)bh * NP_ + n) * 128;
#pragma unroll
    for (int d = 0; d < 16; d++) {
      qrow[c * 16 + d] = qo[d];
      qrow[64 + c * 16 + d] = sqo[d];
      krow[c * 16 + d] = ko[d];
      krow[64 + c * 16 + d] = sko[d];
    }
  }
  float rt = q2 + cqs, ct = k2 + cks;
  rt += __shfl_xor(rt, 1); rt += __shfl_xor(rt, 2);
  ct += __shfl_xor(ct, 1); ct += __shfl_xor(ct, 2);
  if (c == 0) { rowt[(size_t)bh * NP_ + n] = rt; colt[(size_t)bh * NP_ + n] = ct; }
  __syncthreads();
  const int drow = t >> 2;
  const size_t vb = ((size_t)bh * 64 + drow) * NP_ + n0 + c * 16;
#pragma unroll
  for (int i = 0; i < 16; i++) {
    Vt[vb + i] = vts[c * 16 + i][drow];
    CVt[vb + i] = cvts[c * 16 + i][drow];
  }
}

// ---------------- fused attention (R12 form: full dbuf, one barrier/tile) ----------------
__global__ __launch_bounds__(256) void attn_kernel(
    const bf16* __restrict__ Qcat, const bf16* __restrict__ Kcat,
    const bf16* __restrict__ Vt, const bf16* __restrict__ CVt,
    const float* __restrict__ rowt, const float* __restrict__ colt,
    const bf16* __restrict__ bias,
    bf16* __restrict__ ctxm, bf16* __restrict__ ctxc) {
  const int id = blockIdx.x;            // 0..959
  const int xcd = id & 7, slot = id >> 3;
  const int g = xcd + 8 * (slot / 10);  // bh 0..95
  const int it = slot % 10;
  const int b = g / H_, h = g % H_;
  const int bh = g;
  const int i0 = it * 64;
  const int t = threadIdx.x;
  const int lane = t & 63, w = t >> 6;
  const int ln = lane & 15, kg = lane >> 4;
  __shared__ __align__(16) bf16 Ks[2][64 * 128];  // buf0 also hosts Q in prologue
  __shared__ __align__(16) bf16 Vs[2][64 * 64];
  __shared__ __align__(16) bf16 CVs[2][64 * 64];
  __shared__ __align__(16) bf16 Ps[64 * 72];

  const bf16* Qg = Qcat + (size_t)bh * NP_ * 128;
  const bf16* Kg = Kcat + (size_t)bh * NP_ * 128;
  const bf16* Vg = Vt + (size_t)bh * 64 * NP_;
  const bf16* CVg = CVt + (size_t)bh * 64 * NP_;

  auto stageK = [&](int buf, int j0) {
#pragma unroll
    for (int qq = 0; qq < 4; qq++) {
      const int idx = qq * 256 + t;
      const int row = idx >> 4, sl = idx & 15;
      async_cp16(Kg + (size_t)(j0 + row) * 128 + ((sl ^ (row & 7)) * 8),
                 &Ks[buf][(qq * 256 + w * 64) * 8]);
    }
  };
  auto stageV = [&](int buf, int j0) {
#pragma unroll
    for (int qq = 0; qq < 2; qq++) {
      const int idx = qq * 256 + t;
      const int row = idx >> 3, sl = idx & 7;
      async_cp16(Vg + (size_t)row * NP_ + j0 + ((sl ^ (row & 7)) * 8),
                 &Vs[buf][(qq * 256 + w * 64) * 8]);
      async_cp16(CVg + (size_t)row * NP_ + j0 + ((sl ^ (row & 7)) * 8),
                 &CVs[buf][(qq * 256 + w * 64) * 8]);
    }
  };

  // prologue: Q -> Ks[0], K(0) -> Ks[1], V/CV(0) -> buf0
#pragma unroll
  for (int qq = 0; qq < 4; qq++) {
    const int idx = qq * 256 + t;
    const int row = idx >> 4, sl = idx & 15;
    async_cp16(Qg + (size_t)(i0 + row) * 128 + ((sl ^ (row & 7)) * 8),
               &Ks[0][(qq * 256 + w * 64) * 8]);
  }
  stageK(1, 0);
  stageV(0, 0);
  __syncthreads();
  bf16x8 aq[4];
  {
    const int row = w * 16 + ln;
#pragma unroll
    for (int kc = 0; kc < 4; kc++) {
      const int slot2 = kc * 4 + kg;
      aq[kc] = *(const bf16x8*)&Ks[0][row * 128 + ((slot2 ^ (row & 7)) * 8)];
    }
  }
  float rt[4];
#pragma unroll
  for (int r = 0; r < 4; r++) rt[r] = rowt[(size_t)bh * NP_ + i0 + w * 16 + kg * 4 + r];
  __syncthreads();  // all waves done reading Q before jt=0 stages K(1) into Ks[0]

  f32x4 accm[4] = {}, accc[4] = {};
  float den[4] = {0.f, 0.f, 0.f, 0.f};
  const int igb = i0 + w * 16 + kg * 4;

  for (int jt = 0; jt < 10; jt++) {
    const int j0 = jt * 64;
    const int kc2 = (jt + 1) & 1;  // buffer holding K(jt)
    const int vc2 = jt & 1;        // buffer holding V/CV(jt)
    if (jt + 1 < 10) {
      stageK(jt & 1, j0 + 64);
      stageV((jt + 1) & 1, j0 + 64);
    }
    float bb[4][4], ctb[4];
#pragma unroll
    for (int js = 0; js < 4; js++) {
      const int jg = j0 + js * 16 + ln;
      const int jc = jg < N_ ? jg : N_ - 1;
      ctb[js] = colt[(size_t)bh * NP_ + jg];
#pragma unroll
      for (int r = 0; r < 4; r++) {
        const int ic = (igb + r) < N_ ? (igb + r) : N_ - 1;
        bb[js][r] = (float)bias[((size_t)h * N_ + ic) * N_ + jc];
      }
    }
#pragma unroll
    for (int js = 0; js < 4; js++) {
      f32x4 sv = {};
#pragma unroll
      for (int kc = 0; kc < 4; kc++) {
        const int row = js * 16 + ln;
        const int slot2 = kc * 4 + kg;
        bf16x8 bk = *(const bf16x8*)&Ks[kc2][row * 128 + ((slot2 ^ (row & 7)) * 8)];
        sv = __builtin_amdgcn_mfma_f32_16x16x32_bf16(aq[kc], bk, sv, 0, 0, 0);
      }
      const int jg = j0 + js * 16 + ln;
#pragma unroll
      for (int r = 0; r < 4; r++) {
        const float S = 2.0f * sv[r] - rt[r] - ctb[js];
        const float sig = fast_rcp(1.0f + __expf(-S));
        float e = __expf(sig + bb[js][r]);
        if (jg >= N_) e = 0.0f;
        const bf16 eb = (bf16)e;
        den[r] += (float)eb;
        Ps[(w * 16 + kg * 4 + r) * 72 + js * 16 + ln] = eb;
      }
    }
#pragma unroll
    for (int ks = 0; ks < 2; ks++) {
      const int prow = w * 16 + ln;
      bf16x8 pa = *(const bf16x8*)&Ps[prow * 72 + ks * 32 + kg * 8];
      bf16x8 p2a;
#pragma unroll
      for (int i = 0; i < 8; i++) {
        const float pf = (float)pa[i];
        p2a[i] = (bf16)(pf * pf);
      }
#pragma unroll
      for (int nt = 0; nt < 4; nt++) {
        const int vrow = nt * 16 + ln;
        const int slot2 = ks * 4 + kg;
        bf16x8 vb = *(const bf16x8*)&Vs[vc2][vrow * 64 + ((slot2 ^ (vrow & 7)) * 8)];
        bf16x8 cvb = *(const bf16x8*)&CVs[vc2][vrow * 64 + ((slot2 ^ (vrow & 7)) * 8)];
        accm[nt] = __builtin_amdgcn_mfma_f32_16x16x32_bf16(pa, vb, accm[nt], 0, 0, 0);
        accc[nt] = __builtin_amdgcn_mfma_f32_16x16x32_bf16(p2a, cvb, accc[nt], 0, 0, 0);
      }
    }
    __syncthreads();  // ONE barrier per tile: drains next-tile stages + read fence
  }
#pragma unroll
  for (int r = 0; r < 4; r++) {
    float d = den[r];
    d += __shfl_xor(d, 1); d += __shfl_xor(d, 2);
    d += __shfl_xor(d, 4); d += __shfl_xor(d, 8);
    den[r] = d;
  }
#pragma unroll
  for (int r = 0; r < 4; r++) {
    const int ig = i0 + w * 16 + kg * 4 + r;
    if (ig < N_) {
      const float inv = fast_rcp(den[r]);
      const float inv2 = inv * inv;
      const size_t base = (size_t)(b * N_ + ig) * D_ + h * 64;
#pragma unroll
      for (int nt = 0; nt < 4; nt++) {
        ctxm[base + nt * 16 + ln] = (bf16)(accm[nt][r] * inv);
        ctxc[base + nt * 16 + ln] = (bf16)(accc[nt][r] * inv2);
      }
    }
  }
}

// ---------------- host launch ----------------
extern "C" void kernel_launch(void* const* d_in, const int* in_sizes, int n_in,
                              void* d_out, int out_size, void* d_ws, size_t ws_size,
                              hipStream_t stream) {
  const float* x_mean = (const float*)d_in[0];
  const float* x_cov  = (const float*)d_in[1];
  const float* rpb    = (const float*)d_in[2];
  const float* n1w    = (const float*)d_in[3];
  const float* n1b    = (const float*)d_in[4];
  const float* qkvw   = (const float*)d_in[5];
  const float* projw  = (const float*)d_in[6];
  const float* projb  = (const float*)d_in[7];
  const float* cprojw = (const float*)d_in[8];
  const float* cprojb = (const float*)d_in[9];
  const float* n2w    = (const float*)d_in[10];
  const float* n2b    = (const float*)d_in[11];
  const float* fc1w   = (const float*)d_in[12];
  const float* fc1b   = (const float*)d_in[13];
  const float* fc2w   = (const float*)d_in[14];
  const float* fc2b   = (const float*)d_in[15];
  const float* g1     = (const float*)d_in[16];
  const float* g2     = (const float*)d_in[17];
  (void)in_sizes; (void)n_in; (void)out_size; (void)ws_size;

  char* ws = (char*)d_ws;
  size_t off = 0;
  auto take = [&](size_t bytes) {
    char* p = ws + off;
    off += (bytes + 255) & ~(size_t)255;
    return p;
  };
  bf16* wq   = (bf16*)take((size_t)2304 * 768 * 2);
  bf16* wp   = (bf16*)take((size_t)768 * 768 * 2);
  bf16* wcp  = (bf16*)take((size_t)768 * 768 * 2);
  bf16* wf1  = (bf16*)take((size_t)3072 * 768 * 2);
  bf16* wf2  = (bf16*)take((size_t)768 * 3072 * 2);
  bf16* xln  = (bf16*)take((size_t)2 * MP_ * 768 * 2);   // LN out, streams stacked
  char* R    = take((size_t)2 * MP_ * 3072 * 2);          // qkv / mlp-hidden union
  bf16* qkvb = (bf16*)R;                                  // [2MP][2304]
  bf16* hbuf = (bf16*)R;                                  // [2MP][3072]
  bf16* biasb = (bf16*)(R + (size_t)2 * MP_ * 2304 * 2);  // tail gap of R
  bf16* Qcat = (bf16*)take((size_t)BH_ * NP_ * 128 * 2);
  bf16* Kcat = (bf16*)take((size_t)BH_ * NP_ * 128 * 2);
  bf16* Vt   = (bf16*)take((size_t)BH_ * 64 * NP_ * 2);
  bf16* CVt  = (bf16*)take((size_t)BH_ * 64 * NP_ * 2);
  float* rowt = (float*)take((size_t)BH_ * NP_ * 4);
  float* colt = (float*)take((size_t)BH_ * NP_ * 4);
  bf16* ctx  = (bf16*)take((size_t)2 * MP_ * 768 * 2);    // attn out, streams stacked

  float* outm = (float*)d_out;
  float* outc = outm + (size_t)M_ * D_;

  // all weight/bias converts in ONE dispatch
  {
    const int c0 = 2304 * 768 / 4, c1 = 768 * 768 / 4, c2 = 768 * 768 / 4;
    const int c3 = 3072 * 768 / 4, c4 = 768 * 3072 / 4, c5 = H_ * N_ * N_ / 4;
    const int nb = ((c0 + 255) >> 8) + ((c1 + 255) >> 8) + ((c2 + 255) >> 8) +
                   ((c3 + 255) >> 8) + ((c4 + 255) >> 8) + ((c5 + 255) >> 8);
    cvt6_kernel<<<nb, 256, 0, stream>>>(qkvw, projw, cprojw, fc1w, fc2w, rpb,
                                        wq, wp, wcp, wf1, wf2, biasb,
                                        c0, c1, c2, c3, c4, c5);
  }
  // LN1 (both streams, one dispatch)
  ln2_kernel<<<2 * M_, 256, 0, stream>>>(x_mean, x_cov, n1w, n1b, xln);
  // qkv GEMM (both streams, one dispatch)
  gemm_bt<EP_BF16, 768><<<18 * 74, 256, 0, stream>>>(xln, wq, wq, 2304, 18,
      nullptr, nullptr, nullptr, nullptr, nullptr, qkvb, nullptr, nullptr);
  // attention operand prep
  prep_kernel<<<dim3(10, 12, 8), 256, 0, stream>>>(
      qkvb, qkvb + (size_t)MP_ * 2304, Qcat, Kcat, Vt, CVt, rowt, colt);
  // fused attention (XCD-grouped 1-D grid)
  attn_kernel<<<960, 256, 0, stream>>>(Qcat, Kcat, Vt, CVt, rowt, colt, biasb,
                                       ctx, ctx + (size_t)MP_ * 768);
  // proj + residual (writes d_out), per-stream weights
  gemm_bt<EP_PROJ, 768><<<6 * 74, 256, 0, stream>>>(ctx, wp, wcp, 768, 6,
      projb, cprojb, g1, x_mean, x_cov, nullptr, outm, outc);
  // LN2 (both streams, reads d_out)
  ln2_kernel<<<2 * M_, 256, 0, stream>>>(outm, outc, n2w, n2b, xln);
  // fc1 + fast gelu (both streams)
  gemm_bt<EP_GELU, 768><<<24 * 74, 256, 0, stream>>>(xln, wf1, wf1, 3072, 24,
      fc1b, fc1b, nullptr, nullptr, nullptr, hbuf, nullptr, nullptr);
  // fc2, accumulate into d_out (both streams)
  gemm_bt<EP_FC2, 3072><<<6 * 74, 256, 0, stream>>>(hbuf, wf2, wf2, 768, 6,
      fc2b, fc2b, g2, nullptr, nullptr, nullptr, outm, outc);
}